// Round 15
// baseline (189.838 us; speedup 1.0000x reference)
//
#include <hip/hip_runtime.h>

#define C_   256
#define HW_  1024
#define N_   16384
#define K_   8192
#define OUT_SZ   4194304
#define LOSS_OFF 4194304
#define IDX_OFF  4194305
#define MARGIN   0.3f    /* 8.1-sigma of 1-product pairwise score error (sigma~0.037) */

typedef __attribute__((ext_vector_type(8)))  short short8;
typedef __attribute__((ext_vector_type(4)))  float f32x4;
typedef __attribute__((ext_vector_type(16))) float f32x16;

// ---- ws layout (bytes): Rec 8MB | cnorm 32K | ncnorm 32K  (8.45 MB <= proven >=10.26 MB) ----
// d_out scratch: Ah [0,8MB) | Bh [8MB,12MB)  (k_post overwrites after gemm consumed them)
#define REC_OFF    0u
#define CNORM_OFF  8388608u
#define NCNORM_OFF 8421376u
#define WS_NEED    8454144u

// ---- fallback ws layout (round-1 proven) ----
#define FB_CNORM   0u
#define FB_BESTS   32768u
#define FB_BESTK   557056u
#define FB_FIDX    1081344u

__device__ __forceinline__ unsigned short f2bf_rne(float x) {
  unsigned u = __float_as_uint(x);
  unsigned r = (u + 0x7fffu + ((u >> 16) & 1u)) >> 16;
  return (unsigned short)r;
}
__device__ __forceinline__ float bf2f(unsigned short h) {
  return __uint_as_float(((unsigned)h) << 16);
}
__device__ __forceinline__ void gld16(const void* g, void* l) {
  __builtin_amdgcn_global_load_lds((const __attribute__((address_space(1))) unsigned*)g,
                                   (__attribute__((address_space(3))) unsigned*)l, 16, 0, 0);
}
__device__ __forceinline__ float med3(float a, float b, float c) {
#if __has_builtin(__builtin_amdgcn_fmed3f)
  return __builtin_amdgcn_fmed3f(a, b, c);
#else
  return fmaxf(fminf(fmaxf(a, b), c), fminf(a, b));
#endif
}

// fused: blocks [0,2048): emb -> bf16-hi + (+/-)0.5||e||^2; blocks [2048,3072): inp -> bf16-hi A
__global__ __launch_bounds__(256) void conv_fused(const float* __restrict__ inp,
                                                  const float* __restrict__ emb,
                                                  unsigned short* __restrict__ Ah,
                                                  unsigned short* __restrict__ Bh,
                                                  float* __restrict__ cnorm,
                                                  float* __restrict__ ncnorm,
                                                  float* __restrict__ loss_slot) {
  __shared__ float T[64][65];
  int tid = threadIdx.x;
  if (blockIdx.x < 2048) {
    int wave = tid >> 6, lane = tid & 63;
    int k = blockIdx.x * 4 + wave;
    float4 v = *(const float4*)(emb + (size_t)k * C_ + lane * 4);
    float ss = v.x*v.x + v.y*v.y + v.z*v.z + v.w*v.w;
    #pragma unroll
    for (int m = 32; m > 0; m >>= 1) ss += __shfl_xor(ss, m);
    if (lane == 0) { cnorm[k] = 0.5f * ss; ncnorm[k] = -0.5f * ss; }
    uint2 p;
    p.x = (unsigned)f2bf_rne(v.x) | ((unsigned)f2bf_rne(v.y) << 16);
    p.y = (unsigned)f2bf_rne(v.z) | ((unsigned)f2bf_rne(v.w) << 16);
    *(uint2*)&Bh[(size_t)k * C_ + lane * 4] = p;
    if (blockIdx.x == 0 && tid == 0) { *loss_slot = 0.0f; }
  } else {
    int bb = blockIdx.x - 2048;
    int nt = bb >> 2, ct = bb & 3;
    int n0 = nt * 64, c0 = ct * 64;
    int b = n0 >> 10, hw0 = n0 & 1023;
    const float* base = inp + (size_t)b * (C_ * HW_) + hw0;
    #pragma unroll
    for (int i = 0; i < 4; ++i) {                      // float4 reads: 1KB/wave-instr
      int cl = i * 16 + (tid >> 4);
      int h4 = (tid & 15) * 4;
      float4 v = *(const float4*)(base + (size_t)(c0 + cl) * HW_ + h4);
      T[h4 + 0][cl] = v.x; T[h4 + 1][cl] = v.y;        // 2-way LDS (free)
      T[h4 + 2][cl] = v.z; T[h4 + 3][cl] = v.w;
    }
    __syncthreads();
    #pragma unroll
    for (int jp = 0; jp < 2; ++jp) {                   // short8 writes (16B/lane)
      int g = jp * 256 + tid;
      int nl = g >> 3, ch = (g & 7) * 8;
      unsigned short s8[8];
      #pragma unroll
      for (int k = 0; k < 8; ++k) s8[k] = f2bf_rne(T[nl][ch + k]);
      *(uint4*)&Ah[(size_t)(n0 + nl) * C_ + c0 + ch] = *(uint4*)s8;
    }
  }
}

// 1-product hh MFMA GEMM; per-(row, 256-sub) top-3 records -> Rec (ws), nbe-major.
// v14: v8 structure (pure-vmcnt 3-buffer pipeline, XCD swizzle, conflict-free LDS,
// ncnorm-folded acc init, med3 top-3, setprio) with 32x32x16 MFMA shape:
// 16 MFMA/iter @8.07cyc = 129cyc matrix time (was 32 @4.85 = 155, -17%), half the
// issue slots. Same 12 ds_read_b128/iter, same 128 acc regs (8 tiles x f32x16).
// D layout (m74/m101): n(col)=lane&31 -> row; m=(reg&3)+8*(reg>>2)+4*hi -> code.
// Lane owns 2 rows x 64 codes -> top-3 butterfly is ONE shfl_xor(32) (was 2 steps).
__global__ __launch_bounds__(256, 2) void k_gemm1p(const unsigned short* __restrict__ Ah,
                                                   const unsigned short* __restrict__ Bh,
                                                   const float* __restrict__ ncnorm,
                                                   uint4* __restrict__ Rec) {
  __shared__ __align__(16) unsigned short LDS[3][12288];
  __shared__ __align__(16) float ncnL[1024];
  __shared__ float mS[2][128][3];

  const int tid = threadIdx.x, lane = tid & 63, wave = tid >> 6;
  const int wr = wave >> 1, wc = wave & 1;
  const int bid = (int)blockIdx.x;
  const int wg = (bid & 7) * 128 + (bid >> 3);         // bijective XCD-chunk swizzle
  const int rb = wg >> 3, kb = wg & 7;
  const int row0 = rb * 128;
  const int l31 = lane & 31, hi = lane >> 5;

  // staging (identical to v8): thread g stages row g>>2, slot g&3 holds chunk (g&3)^((row>>1)&3)
  const char* srcA[2]; int dstA[2];
  #pragma unroll
  for (int t = 0; t < 2; ++t) {
    int g = t * 256 + tid;
    int row = g >> 2, chs = g & 3, ch = chs ^ ((row >> 1) & 3);
    srcA[t] = (const char*)Ah + (size_t)(row0 + row) * 512 + ch * 16;
    dstA[t] = g * 16;
  }
  const char* srcB[4]; int dstB[4];
  #pragma unroll
  for (int t = 0; t < 4; ++t) {
    int g = t * 256 + tid;
    int r = g >> 2, chs = g & 3, ch = chs ^ ((r >> 1) & 3);
    srcB[t] = (const char*)Bh + (size_t)(kb * 1024 + r) * 512 + ch * 16;
    dstB[t] = 8192 + g * 16;
  }

  // fragment read bases (bytes): rows region [0,8192), codes region [8192,24576)
  int rbase[2], rswz[2];                               // rows: r = wr*64 + s*32 + l31
  #pragma unroll
  for (int s = 0; s < 2; ++s) {
    int r = wr * 64 + s * 32 + l31;
    rbase[s] = r * 64; rswz[s] = (r >> 1) & 3;
  }
  int cbase[4], cswz[4];                               // codes: r = wc*128 + t*32 + l31
  #pragma unroll
  for (int t = 0; t < 4; ++t) {
    int r = wc * 128 + t * 32 + l31;
    cbase[t] = 8192 + r * 64; cswz[t] = (r >> 1) & 3;
  }

  // prologue: ncnorm (oldest) + tile 0 -> buf0 + tile 1 -> buf1; retire ONLY ncnorm.
  gld16((const char*)ncnorm + (size_t)kb * 4096 + tid * 16, (char*)ncnL + tid * 16);
  #pragma unroll
  for (int t = 0; t < 2; ++t) gld16(srcA[t], (char*)LDS[0] + dstA[t]);
  #pragma unroll
  for (int t = 0; t < 4; ++t) gld16(srcB[t], (char*)LDS[0] + dstB[t]);
  #pragma unroll
  for (int t = 0; t < 2; ++t) gld16(srcA[t] + 64, (char*)LDS[1] + dstA[t]);
  #pragma unroll
  for (int t = 0; t < 4; ++t) gld16(srcB[t] + 64, (char*)LDS[1] + dstB[t]);
  asm volatile("s_waitcnt vmcnt(12)" ::: "memory");     // ncnorm landed; 12 stages fly
  __builtin_amdgcn_s_barrier();

  const unsigned wq  = (unsigned)(wc * 128 + hi * 4);  // embed bits 7, 2
  const unsigned kmk = 0xFFFFFF00u;

  int cur = 0, nst = 2;                 // read buffer (it%3), stage buffer ((it+2)%3)

  for (int sub = 0; sub < 4; ++sub) {
    const int nbe = kb * 4 + sub;
    // acc init = -cnorm; lane's codes per tile t: t*32 + {0..3,8..11,16..19,24..27} + 4*hi
    f32x16 acc[2][4];
    {
      const int nb = sub * 256 + wc * 128 + hi * 4;
      #pragma unroll
      for (int t = 0; t < 4; ++t) {
        float4 n0 = *(const float4*)&ncnL[nb + t * 32 + 0];
        float4 n1 = *(const float4*)&ncnL[nb + t * 32 + 8];
        float4 n2 = *(const float4*)&ncnL[nb + t * 32 + 16];
        float4 n3 = *(const float4*)&ncnL[nb + t * 32 + 24];
        #pragma unroll
        for (int s = 0; s < 2; ++s) {
          acc[s][t][0]  = n0.x; acc[s][t][1]  = n0.y; acc[s][t][2]  = n0.z; acc[s][t][3]  = n0.w;
          acc[s][t][4]  = n1.x; acc[s][t][5]  = n1.y; acc[s][t][6]  = n1.z; acc[s][t][7]  = n1.w;
          acc[s][t][8]  = n2.x; acc[s][t][9]  = n2.y; acc[s][t][10] = n2.z; acc[s][t][11] = n2.w;
          acc[s][t][12] = n3.x; acc[s][t][13] = n3.y; acc[s][t][14] = n3.z; acc[s][t][15] = n3.w;
        }
      }
    }

    #pragma unroll 2
    for (int ci = 0; ci < 8; ++ci) {
      const int it = (sub << 3) | ci;
      if (it < 31) asm volatile("s_waitcnt vmcnt(6)" ::: "memory");
      else         asm volatile("s_waitcnt vmcnt(0)" ::: "memory");
      __builtin_amdgcn_s_barrier();
      __builtin_amdgcn_sched_barrier(0);

      if (it + 2 < 32) {
        const int nt2 = it + 2, nsub = nt2 >> 3, nci = nt2 & 7;
        #pragma unroll
        for (int t = 0; t < 2; ++t)
          gld16(srcA[t] + nci * 64, (char*)LDS[nst] + dstA[t]);
        #pragma unroll
        for (int t = 0; t < 4; ++t)
          gld16(srcB[t] + (size_t)nsub * 131072 + nci * 64, (char*)LDS[nst] + dstB[t]);
      }

      const char* Lb = (const char*)&LDS[cur][0];
      #pragma unroll
      for (int kk = 0; kk < 2; ++kk) {                 // k-step: frag k = kk*16 + hi*8 + j
        const int c = kk * 2 + hi;                     // 8-elem k-chunk index
        short8 rf0 = *(const short8*)(Lb + rbase[0] + ((c ^ rswz[0]) * 16));
        short8 rf1 = *(const short8*)(Lb + rbase[1] + ((c ^ rswz[1]) * 16));
        short8 cf0 = *(const short8*)(Lb + cbase[0] + ((c ^ cswz[0]) * 16));
        short8 cf1 = *(const short8*)(Lb + cbase[1] + ((c ^ cswz[1]) * 16));
        short8 cf2 = *(const short8*)(Lb + cbase[2] + ((c ^ cswz[2]) * 16));
        short8 cf3 = *(const short8*)(Lb + cbase[3] + ((c ^ cswz[3]) * 16));
        __builtin_amdgcn_s_setprio(1);
        acc[0][0] = __builtin_amdgcn_mfma_f32_32x32x16_bf16(cf0, rf0, acc[0][0], 0, 0, 0);
        acc[0][1] = __builtin_amdgcn_mfma_f32_32x32x16_bf16(cf1, rf0, acc[0][1], 0, 0, 0);
        acc[0][2] = __builtin_amdgcn_mfma_f32_32x32x16_bf16(cf2, rf0, acc[0][2], 0, 0, 0);
        acc[0][3] = __builtin_amdgcn_mfma_f32_32x32x16_bf16(cf3, rf0, acc[0][3], 0, 0, 0);
        acc[1][0] = __builtin_amdgcn_mfma_f32_32x32x16_bf16(cf0, rf1, acc[1][0], 0, 0, 0);
        acc[1][1] = __builtin_amdgcn_mfma_f32_32x32x16_bf16(cf1, rf1, acc[1][1], 0, 0, 0);
        acc[1][2] = __builtin_amdgcn_mfma_f32_32x32x16_bf16(cf2, rf1, acc[1][2], 0, 0, 0);
        acc[1][3] = __builtin_amdgcn_mfma_f32_32x32x16_bf16(cf3, rf1, acc[1][3], 0, 0, 0);
        __builtin_amdgcn_s_setprio(0);
      }
      cur = (cur == 2) ? 0 : cur + 1;
      nst = (nst == 2) ? 0 : nst + 1;
    }

    // epilogue: lane owns rows wr*64 + s*32 + l31 (s=0,1); per row 64 codes in-register.
    // code = t*32 + (reg&3) + 8*(reg>>2) + 4*hi; key = score bits | local code index.
    #pragma unroll
    for (int s = 0; s < 2; ++s) {
      float t1 = -3.4e38f, t2 = t1, t3 = t1;
      #pragma unroll
      for (int t = 0; t < 4; ++t)
        #pragma unroll
        for (int reg = 0; reg < 16; ++reg) {
          unsigned idxv = wq | (unsigned)(t * 32 + (reg & 3) + 8 * (reg >> 2));
          float kf = __uint_as_float((__float_as_uint(acc[s][t][reg]) & kmk) | idxv);
          float n3 = med3(t2, kf, t3);
          float n2 = med3(t1, kf, t2);
          t1 = fmaxf(t1, kf);
          t2 = n2; t3 = n3;
        }
      {                                                // merge hi halves (1 step)
        float b1 = __shfl_xor(t1, 32), b2 = __shfl_xor(t2, 32), b3 = __shfl_xor(t3, 32);
        float n3 = med3(t2, b1, t3);
        float n2 = med3(t1, b1, t2);
        t1 = fmaxf(t1, b1); t2 = n2; t3 = n3;
        n3 = med3(t2, b2, t3); t2 = fmaxf(t2, b2); t3 = n3;
        t3 = fmaxf(t3, b3);
      }
      if (hi == 0) {
        int rowl = wr * 64 + s * 32 + l31;
        mS[wc][rowl][0] = t1; mS[wc][rowl][1] = t2; mS[wc][rowl][2] = t3;
      }
    }
    asm volatile("s_waitcnt lgkmcnt(0)" ::: "memory");
    __builtin_amdgcn_s_barrier();
    __builtin_amdgcn_sched_barrier(0);
    if (tid < 128) {
      float s1 = mS[0][tid][0], s2 = mS[0][tid][1], s3 = mS[0][tid][2];
      float b1 = mS[1][tid][0], b2 = mS[1][tid][1], b3 = mS[1][tid][2];
      float n3 = med3(s2, b1, s3);
      float n2 = med3(s1, b1, s2);
      s1 = fmaxf(s1, b1); s2 = n2; s3 = n3;
      n3 = med3(s2, b2, s3); s2 = fmaxf(s2, b2); s3 = n3;
      s3 = fmaxf(s3, b3);
      unsigned u1 = __float_as_uint(s1), u2 = __float_as_uint(s2), u3 = __float_as_uint(s3);
      uint4 rec;
      rec.x = u1 & kmk;
      rec.y = ((unsigned)f2bf_rne(__uint_as_float(u2 & kmk)) << 16)
            |  (unsigned)f2bf_rne(__uint_as_float(u3 & kmk));
      rec.z = (u1 & 255u) | ((u2 & 255u) << 8) | ((u3 & 255u) << 16);
      rec.w = 0u;
      Rec[(size_t)nbe * N_ + row0 + tid] = rec;
    }
  }
}

// fused post, v9: 16-row tiles (grid 1024 -> 4 blocks/CU, 16 waves/CU) and
// WAVE-parallel refine (each wave owns a flagged row; no block-serial chain).
__global__ __launch_bounds__(256) void k_post(const float* __restrict__ inp,
                                              const float* __restrict__ emb,
                                              const float* __restrict__ cnorm,
                                              const uint4* __restrict__ Rec,
                                              float* __restrict__ out,
                                              float* __restrict__ outIdx,
                                              float* __restrict__ loss) {
  __shared__ float Q[16][258];        // pad 258: out-phase column reads 2-way (free)
  __shared__ float gS[16];
  __shared__ int   ridx[16];
  __shared__ int   flist[16];
  __shared__ int   ckw[4][96];
  __shared__ float cscw[4][96];
  __shared__ int   ncw[4];
  __shared__ int   nflag;
  __shared__ float red[4];

  const int tid = threadIdx.x;
  const int n0 = blockIdx.x * 16, b = n0 >> 10, hw0 = n0 & 1023;
  const int lane = tid & 63, wv = tid >> 6;

  // ---- decide: 16 threads per row (2 subs each), shfl-reduce over 16-lane group ----
  const int r = tid >> 4, j = tid & 15;
  const int row = n0 + r;
  uint4 rv[2];
  rv[0] = Rec[(size_t)(2 * j)     * N_ + row];
  rv[1] = Rec[(size_t)(2 * j + 1) * N_ + row];
  float m1 = -3.4e38f; int gk = 0x7fffffff;
  #pragma unroll
  for (int q = 0; q < 2; ++q) {                  // ascending sub: ties keep lowest gk
    float s1 = __uint_as_float(rv[q].x);
    int  kk = (2 * j + q) * 256 + (int)(rv[q].z & 255u);
    if (s1 > m1) { m1 = s1; gk = kk; }
  }
  #pragma unroll
  for (int m = 1; m < 16; m <<= 1) {
    float so = __shfl_xor(m1, m); int ko = __shfl_xor(gk, m);
    if (so > m1 || (so == m1 && ko < gk)) { m1 = so; gk = ko; }
  }
  float thr = m1 - MARGIN;
  int cnt = 0;
  #pragma unroll
  for (int q = 0; q < 2; ++q) {
    uint4 v = rv[q];
    cnt += (__uint_as_float(v.x) >= thr);
    cnt += (bf2f((unsigned short)(v.y >> 16)) >= thr);
    cnt += (bf2f((unsigned short)(v.y & 0xffffu)) >= thr);
  }
  #pragma unroll
  for (int m = 1; m < 16; m <<= 1) cnt += __shfl_xor(cnt, m);
  if (tid == 0) nflag = 0;
  __syncthreads();
  if (j == 0) {
    gS[r] = m1;
    if (cnt == 1) { ridx[r] = gk; }
    else { int p = atomicAdd(&nflag, 1); flist[p] = r; }
  }
  __syncthreads();

  // ---- wave-parallel exact refine (rare): wave wv handles rows wv, wv+4, ... ----
  int nf = nflag;
  for (int i = wv; i < nf; i += 4) {
    int lr = flist[i];
    int rw = n0 + lr;
    float fr[4];
    #pragma unroll
    for (int k = 0; k < 4; ++k)
      fr[k] = inp[(size_t)b * (C_ * HW_) + (size_t)(lane * 4 + k) * HW_ + (rw & 1023)];
    float th2 = gS[lr] - MARGIN;
    if (lane == 0) ncw[wv] = 0;
    if (lane < 32) {
      uint4 v = Rec[(size_t)lane * N_ + rw];
      float s1 = __uint_as_float(v.x);
      float s2 = bf2f((unsigned short)(v.y >> 16));
      float s3 = bf2f((unsigned short)(v.y & 0xffffu));
      int bb = lane * 256;
      if (s1 >= th2) { int p = atomicAdd(&ncw[wv], 1); ckw[wv][p] = bb + (int)(v.z & 255u); }
      if (s2 >= th2) { int p = atomicAdd(&ncw[wv], 1); ckw[wv][p] = bb + (int)((v.z >> 8) & 255u); }
      if (s3 >= th2) { int p = atomicAdd(&ncw[wv], 1); ckw[wv][p] = bb + (int)((v.z >> 16) & 255u); }
    }
    int nc = ncw[wv];                                  // same-wave DS ordering
    for (int c = 0; c < nc; ++c) {
      int k = ckw[wv][c];
      float4 e = ((const float4*)(emb + (size_t)k * C_))[lane];
      float d = fr[0]*e.x + fr[1]*e.y + fr[2]*e.z + fr[3]*e.w;
      #pragma unroll
      for (int m = 32; m > 0; m >>= 1) d += __shfl_xor(d, m);
      if (lane == 0) cscw[wv][c] = d - cnorm[k];
    }
    if (lane == 0) {
      float bs = cscw[wv][0]; int bk = ckw[wv][0];
      for (int c = 1; c < nc; ++c)
        if (cscw[wv][c] > bs || (cscw[wv][c] == bs && ckw[wv][c] < bk)) { bs = cscw[wv][c]; bk = ckw[wv][c]; }
      ridx[lr] = bk;
    }
  }
  __syncthreads();

  // ---- idx outputs + emb gather (1 float4/thread/pass: wave = one full emb row) ----
  if (tid < 16) outIdx[n0 + tid] = (float)ridx[tid];
  #pragma unroll
  for (int p = 0; p < 4; ++p) {
    int g = p * 256 + tid;
    int rr = g >> 6, c4 = (g & 63) * 4;
    int kq = ridx[rr];
    *(float4*)&Q[rr][c4] = *(const float4*)(emb + (size_t)kq * C_ + c4);
  }
  __syncthreads();

  // ---- NCHW out + loss: float4 on hw (full-line 64B segments) ----
  float lsum = 0.0f;
  const int hw4 = (tid & 3) * 4, cl = tid >> 2;
  #pragma unroll
  for (int p = 0; p < 4; ++p) {
    int c = p * 64 + cl;
    size_t a = (size_t)b * (C_ * HW_) + (size_t)c * HW_ + hw0 + hw4;
    float4 x = *(const float4*)(inp + a);
    float4 q;
    q.x = Q[hw4 + 0][c]; q.y = Q[hw4 + 1][c];
    q.z = Q[hw4 + 2][c]; q.w = Q[hw4 + 3][c];
    *(float4*)(out + a) = q;
    float d0 = q.x - x.x, d1 = q.y - x.y, d2 = q.z - x.z, d3 = q.w - x.w;
    lsum += d0*d0 + d1*d1 + d2*d2 + d3*d3;
  }
  #pragma unroll
  for (int m = 32; m > 0; m >>= 1) lsum += __shfl_xor(lsum, m);
  if ((tid & 63) == 0) red[tid >> 6] = lsum;
  __syncthreads();
  if (tid == 0)
    atomicAdd(loss, (red[0] + red[1] + red[2] + red[3]) * (0.25f / (float)OUT_SZ));
}

// ---------------- fallback path (round-1 fp32, proven) ----------------
__global__ __launch_bounds__(256) void k_norms_fb(const float* __restrict__ emb,
                                                  float* __restrict__ cnorm,
                                                  float* __restrict__ loss_slot) {
  int tid = threadIdx.x, wave = tid >> 6, lane = tid & 63;
  int k = blockIdx.x * 4 + wave;
  float4 v = *(const float4*)(emb + k * C_ + lane * 4);
  float s = v.x*v.x + v.y*v.y + v.z*v.z + v.w*v.w;
  #pragma unroll
  for (int m = 32; m > 0; m >>= 1) s += __shfl_xor(s, m);
  if (lane == 0) cnorm[k] = 0.5f * s;
  if (blockIdx.x == 0 && tid == 0) *loss_slot = 0.0f;
}

__global__ __launch_bounds__(256) void k_score_fb(const float* __restrict__ inp,
                                                  const float* __restrict__ emb,
                                                  const float* __restrict__ cnorm,
                                                  float* __restrict__ bestS,
                                                  int*   __restrict__ bestK) {
  __shared__ float As[16][132];
  __shared__ float Bs[16][132];
  const int tid = threadIdx.x;
  const int tx = tid & 15, ty = tid >> 4;
  const int rt = blockIdx.x >> 3, ks = blockIdx.x & 7;
  const int row0 = rt * 128;
  const float* Abase = inp + (row0 >> 10) * (C_ * HW_) + (row0 & 1023);
  const int kbase = ks * 1024;
  const int m4  = (tid & 31) << 2;
  const int ccA = tid >> 5;
  const int cc4 = (tid & 3) << 2;
  const int kkB = tid >> 2;

  float rS[8]; int rK[8];
  #pragma unroll
  for (int r = 0; r < 8; ++r) { rS[r] = -3.4e38f; rK[r] = 0; }

  for (int kt = 0; kt < 8; ++kt) {
    const int k0 = kbase + kt * 128;
    float acc[8][8];
    #pragma unroll
    for (int r = 0; r < 8; ++r)
      #pragma unroll
      for (int c = 0; c < 8; ++c) acc[r][c] = 0.f;

    for (int ci = 0; ci < 16; ++ci) {
      const int c0 = ci * 16;
      __syncthreads();
      #pragma unroll
      for (int p = 0; p < 2; ++p) {
        int cc = ccA + p * 8;
        float4 v = *(const float4*)(Abase + (c0 + cc) * HW_ + m4);
        *(float4*)(&As[cc][m4]) = v;
      }
      #pragma unroll
      for (int p = 0; p < 2; ++p) {
        int k = kkB + p * 64;
        float4 v = *(const float4*)(emb + (size_t)(k0 + k) * C_ + c0 + cc4);
        Bs[cc4 + 0][k] = v.x; Bs[cc4 + 1][k] = v.y;
        Bs[cc4 + 2][k] = v.z; Bs[cc4 + 3][k] = v.w;
      }
      __syncthreads();
      #pragma unroll
      for (int cc = 0; cc < 16; ++cc) {
        float4 a0 = *(const float4*)(&As[cc][ty * 8]);
        float4 a1 = *(const float4*)(&As[cc][ty * 8 + 4]);
        float4 b0 = *(const float4*)(&Bs[cc][tx * 8]);
        float4 b1 = *(const float4*)(&Bs[cc][tx * 8 + 4]);
        float a[8] = {a0.x, a0.y, a0.z, a0.w, a1.x, a1.y, a1.z, a1.w};
        float b[8] = {b0.x, b0.y, b0.z, b0.w, b1.x, b1.y, b1.z, b1.w};
        #pragma unroll
        for (int r = 0; r < 8; ++r)
          #pragma unroll
          for (int c = 0; c < 8; ++c) acc[r][c] += a[r] * b[c];
      }
    }
    float cn[8];
    {
      float4 c0v = *(const float4*)(cnorm + k0 + tx * 8);
      float4 c1v = *(const float4*)(cnorm + k0 + tx * 8 + 4);
      cn[0] = c0v.x; cn[1] = c0v.y; cn[2] = c0v.z; cn[3] = c0v.w;
      cn[4] = c1v.x; cn[5] = c1v.y; cn[6] = c1v.z; cn[7] = c1v.w;
    }
    #pragma unroll
    for (int r = 0; r < 8; ++r)
      #pragma unroll
      for (int c = 0; c < 8; ++c) {
        float s = acc[r][c] - cn[c];
        if (s > rS[r]) { rS[r] = s; rK[r] = k0 + tx * 8 + c; }
      }
  }
  #pragma unroll
  for (int r = 0; r < 8; ++r) {
    float s = rS[r]; int kk = rK[r];
    #pragma unroll
    for (int m = 1; m < 16; m <<= 1) {
      float so = __shfl_xor(s, m);
      int   ko = __shfl_xor(kk, m);
      if (so > s || (so == s && ko < kk)) { s = so; kk = ko; }
    }
    if (tx == 0) {
      int row = row0 + ty * 8 + r;
      bestS[ks * N_ + row] = s;
      bestK[ks * N_ + row] = kk;
    }
  }
}

__global__ __launch_bounds__(256) void k_merge_fb(const float* __restrict__ bestS,
                                                  const int*   __restrict__ bestK,
                                                  float* __restrict__ out_idx,
                                                  int*   __restrict__ fidx) {
  int n = blockIdx.x * 256 + threadIdx.x;
  float bs = -3.4e38f; int bk = 0x7fffffff;
  #pragma unroll
  for (int s = 0; s < 8; ++s) {
    float v = bestS[s * N_ + n];
    int  kk = bestK[s * N_ + n];
    if (v > bs || (v == bs && kk < bk)) { bs = v; bk = kk; }
  }
  out_idx[n] = (float)bk;
  fidx[n] = bk;
}

__global__ __launch_bounds__(256) void k_out_fb(const float* __restrict__ inp,
                                                const float* __restrict__ emb,
                                                const int* __restrict__ fidx,
                                                float* __restrict__ out,
                                                float* __restrict__ loss) {
  __shared__ float Q[32][260];
  int tid = threadIdx.x;
  int n0 = blockIdx.x * 32, b = n0 >> 10, hw0 = n0 & 1023;
  #pragma unroll
  for (int p = 0; p < 8; ++p) {
    int r = p * 4 + (tid >> 6);
    int kq = fidx[n0 + r];
    float4 v = *(const float4*)(emb + (size_t)kq * C_ + (tid & 63) * 4);
    *(float4*)&Q[r][(tid & 63) * 4] = v;
  }
  __syncthreads();
  int hwl = tid & 31, cl = tid >> 5;
  float lsum = 0.0f;
  #pragma unroll
  for (int p = 0; p < 32; ++p) {
    int c = p * 8 + cl;
    size_t a = (size_t)b * (C_ * HW_) + (size_t)c * HW_ + hw0 + hwl;
    float q = Q[hwl][c];
    float x = inp[a];
    out[a] = q;
    float dd = q - x; lsum += dd * dd;
  }
  #pragma unroll
  for (int m = 32; m > 0; m >>= 1) lsum += __shfl_xor(lsum, m);
  __shared__ float red[4];
  if ((tid & 63) == 0) red[tid >> 6] = lsum;
  __syncthreads();
  if (tid == 0)
    atomicAdd(loss, (red[0] + red[1] + red[2] + red[3]) * (0.25f / (float)OUT_SZ));
}

extern "C" void kernel_launch(void* const* d_in, const int* in_sizes, int n_in,
                              void* d_out, int out_size, void* d_ws, size_t ws_size,
                              hipStream_t stream) {
  const float* inp = (const float*)d_in[0];
  const float* emb = (const float*)d_in[1];
  float* out = (float*)d_out;
  char* ws = (char*)d_ws;

  if (ws_size >= (size_t)WS_NEED) {
    unsigned short* Ah = (unsigned short*)d_out;                      // [0, 8MB) of d_out
    unsigned short* Bh = (unsigned short*)((char*)d_out + 8388608u);  // [8MB, 12MB) of d_out
    uint4* Rec     = (uint4*)(ws + REC_OFF);                          // ws [0, 8MB)
    float* cnorm   = (float*)(ws + CNORM_OFF);
    float* ncnorm  = (float*)(ws + NCNORM_OFF);

    conv_fused <<<3072,  256, 0, stream>>>(inp, emb, Ah, Bh, cnorm, ncnorm,
                                           out + LOSS_OFF);
    k_gemm1p   <<<1024,  256, 0, stream>>>(Ah, Bh, ncnorm, Rec);
    k_post     <<<N_/16, 256, 0, stream>>>(inp, emb, cnorm, Rec, out,
                                           out + IDX_OFF, out + LOSS_OFF);
  } else {
    float* cnorm = (float*)(ws + FB_CNORM);
    float* bestS = (float*)(ws + FB_BESTS);
    int*   bestK = (int*)(ws + FB_BESTK);
    int*   fidx  = (int*)(ws + FB_FIDX);

    k_norms_fb <<<K_ / 4, 256, 0, stream>>>(emb, cnorm, out + LOSS_OFF);
    k_score_fb <<<1024,   256, 0, stream>>>(inp, emb, cnorm, bestS, bestK);
    k_merge_fb <<<N_/256, 256, 0, stream>>>(bestS, bestK, out + IDX_OFF, fidx);
    k_out_fb   <<<OUT_SZ/8192, 256, 0, stream>>>(inp, emb, fidx, out, out + LOSS_OFF);
  }
}

// Round 16
// 181.033 us; speedup vs baseline: 1.0486x; 1.0486x over previous
//
#include <hip/hip_runtime.h>

#define C_   256
#define HW_  1024
#define N_   16384
#define K_   8192
#define OUT_SZ   4194304
#define LOSS_OFF 4194304
#define IDX_OFF  4194305
#define MARGIN   0.3f    /* 8.1-sigma of 1-product pairwise score error (sigma~0.037) */

typedef __attribute__((ext_vector_type(8)))  short short8;
typedef __attribute__((ext_vector_type(4)))  float f32x4;

// ---- ws layout (bytes): Rec 8MB | cnorm 32K | ncnorm 32K  (8.45 MB <= proven >=10.26 MB) ----
// d_out scratch: Ah [0,8MB) | Bh [8MB,12MB)  (k_post overwrites after gemm consumed them)
#define REC_OFF    0u
#define CNORM_OFF  8388608u
#define NCNORM_OFF 8421376u
#define WS_NEED    8454144u

// ---- fallback ws layout (round-1 proven) ----
#define FB_CNORM   0u
#define FB_BESTS   32768u
#define FB_BESTK   557056u
#define FB_FIDX    1081344u

__device__ __forceinline__ unsigned short f2bf_rne(float x) {
  unsigned u = __float_as_uint(x);
  unsigned r = (u + 0x7fffu + ((u >> 16) & 1u)) >> 16;
  return (unsigned short)r;
}
__device__ __forceinline__ float bf2f(unsigned short h) {
  return __uint_as_float(((unsigned)h) << 16);
}
__device__ __forceinline__ void gld16(const void* g, void* l) {
  __builtin_amdgcn_global_load_lds((const __attribute__((address_space(1))) unsigned*)g,
                                   (__attribute__((address_space(3))) unsigned*)l, 16, 0, 0);
}
__device__ __forceinline__ float med3(float a, float b, float c) {
#if __has_builtin(__builtin_amdgcn_fmed3f)
  return __builtin_amdgcn_fmed3f(a, b, c);
#else
  return fmaxf(fminf(fmaxf(a, b), c), fminf(a, b));
#endif
}

// fused: blocks [0,2048): emb -> bf16-hi + (+/-)0.5||e||^2; blocks [2048,3072): inp -> bf16-hi A
// v9: inp-part vectorized: float4 global reads (1KB/wave-instr), short8 Ah writes.
__global__ __launch_bounds__(256) void conv_fused(const float* __restrict__ inp,
                                                  const float* __restrict__ emb,
                                                  unsigned short* __restrict__ Ah,
                                                  unsigned short* __restrict__ Bh,
                                                  float* __restrict__ cnorm,
                                                  float* __restrict__ ncnorm,
                                                  float* __restrict__ loss_slot) {
  __shared__ float T[64][65];
  int tid = threadIdx.x;
  if (blockIdx.x < 2048) {
    int wave = tid >> 6, lane = tid & 63;
    int k = blockIdx.x * 4 + wave;
    float4 v = *(const float4*)(emb + (size_t)k * C_ + lane * 4);
    float ss = v.x*v.x + v.y*v.y + v.z*v.z + v.w*v.w;
    #pragma unroll
    for (int m = 32; m > 0; m >>= 1) ss += __shfl_xor(ss, m);
    if (lane == 0) { cnorm[k] = 0.5f * ss; ncnorm[k] = -0.5f * ss; }
    uint2 p;
    p.x = (unsigned)f2bf_rne(v.x) | ((unsigned)f2bf_rne(v.y) << 16);
    p.y = (unsigned)f2bf_rne(v.z) | ((unsigned)f2bf_rne(v.w) << 16);
    *(uint2*)&Bh[(size_t)k * C_ + lane * 4] = p;
    if (blockIdx.x == 0 && tid == 0) { *loss_slot = 0.0f; }
  } else {
    int bb = blockIdx.x - 2048;
    int nt = bb >> 2, ct = bb & 3;
    int n0 = nt * 64, c0 = ct * 64;
    int b = n0 >> 10, hw0 = n0 & 1023;
    const float* base = inp + (size_t)b * (C_ * HW_) + hw0;
    #pragma unroll
    for (int i = 0; i < 4; ++i) {                      // float4 reads: 1KB/wave-instr
      int cl = i * 16 + (tid >> 4);
      int h4 = (tid & 15) * 4;
      float4 v = *(const float4*)(base + (size_t)(c0 + cl) * HW_ + h4);
      T[h4 + 0][cl] = v.x; T[h4 + 1][cl] = v.y;        // 2-way LDS (free)
      T[h4 + 2][cl] = v.z; T[h4 + 3][cl] = v.w;
    }
    __syncthreads();
    #pragma unroll
    for (int jp = 0; jp < 2; ++jp) {                   // short8 writes (16B/lane)
      int g = jp * 256 + tid;
      int nl = g >> 3, ch = (g & 7) * 8;
      unsigned short s8[8];
      #pragma unroll
      for (int k = 0; k < 8; ++k) s8[k] = f2bf_rne(T[nl][ch + k]);
      *(uint4*)&Ah[(size_t)(n0 + nl) * C_ + c0 + ch] = *(uint4*)s8;
    }
  }
}

// 1-product hh MFMA GEMM; per-(row, 256-sub) top-3 records -> Rec (ws), nbe-major.
// v8 FINAL (97us equilibrium; spill-free 112+128 regs, 2 waves/SIMD, 0 bank conflicts):
// pure-vmcnt 3-buffer pipeline, XCD swizzle, conflict-free LDS (16-row fragment span
// matches the 4-slot XOR swizzle period), ncnorm-folded acc init, med3 top-3, setprio.
// Closed avenues, each with mechanism: 256^2 m201 geometry (spills: 128 acc + operands
// > 256-reg cap); 32x32x16 shape (32-row fragment span -> 4-way bank conflict, 6.29M);
// sync variants drain/counted-3buf/pure-counted (all ~97: occupancy-capped latency
// equilibrium, no pipe >39%).
__global__ __launch_bounds__(256, 2) void k_gemm1p(const unsigned short* __restrict__ Ah,
                                                   const unsigned short* __restrict__ Bh,
                                                   const float* __restrict__ ncnorm,
                                                   uint4* __restrict__ Rec) {
  __shared__ __align__(16) unsigned short LDS[3][12288];
  __shared__ __align__(16) float ncnL[1024];
  __shared__ float mS[2][128][3];

  const int tid = threadIdx.x, lane = tid & 63, wave = tid >> 6;
  const int wr = wave >> 1, wc = wave & 1;
  const int bid = (int)blockIdx.x;
  const int wg = (bid & 7) * 128 + (bid >> 3);         // bijective XCD-chunk swizzle
  const int rb = wg >> 3, kb = wg & 7;
  const int row0 = rb * 128;
  const int qm = lane & 15, quad = lane >> 4;
  const int sw = (quad ^ ((qm >> 1) & 3)) * 8;         // conflict-free XOR swizzle (v6)

  const char* srcA[2]; int dstA[2];
  #pragma unroll
  for (int t = 0; t < 2; ++t) {
    int g = t * 256 + tid;
    int row = g >> 2, chs = g & 3, ch = chs ^ ((row >> 1) & 3);
    srcA[t] = (const char*)Ah + (size_t)(row0 + row) * 512 + ch * 16;
    dstA[t] = g * 16;
  }
  const char* srcB[4]; int dstB[4];
  #pragma unroll
  for (int t = 0; t < 4; ++t) {
    int g = t * 256 + tid;
    int r = g >> 2, chs = g & 3, ch = chs ^ ((r >> 1) & 3);
    srcB[t] = (const char*)Bh + (size_t)(kb * 1024 + r) * 512 + ch * 16;
    dstB[t] = 8192 + g * 16;
  }

  // prologue: ncnorm (oldest) + tile 0 -> buf0 + tile 1 -> buf1; retire ONLY ncnorm.
  gld16((const char*)ncnorm + (size_t)kb * 4096 + tid * 16, (char*)ncnL + tid * 16);
  #pragma unroll
  for (int t = 0; t < 2; ++t) gld16(srcA[t], (char*)LDS[0] + dstA[t]);
  #pragma unroll
  for (int t = 0; t < 4; ++t) gld16(srcB[t], (char*)LDS[0] + dstB[t]);
  #pragma unroll
  for (int t = 0; t < 2; ++t) gld16(srcA[t] + 64, (char*)LDS[1] + dstA[t]);
  #pragma unroll
  for (int t = 0; t < 4; ++t) gld16(srcB[t] + 64, (char*)LDS[1] + dstB[t]);
  asm volatile("s_waitcnt vmcnt(12)" ::: "memory");     // ncnorm landed; 12 stages fly
  __builtin_amdgcn_s_barrier();

  const unsigned wq  = (unsigned)(wc * 128 + quad * 4);        // embed bits 7, 3:2
  const unsigned kmk = 0xFFFFFF00u;

  int cur = 0, nst = 2;                 // read buffer (it%3), stage buffer ((it+2)%3)

  for (int sub = 0; sub < 4; ++sub) {
    const int nbe = kb * 4 + sub;
    const int nb4 = sub * 256 + wc * 128 + quad * 4;
    f32x4 acc[4][8];
    {
      float4 ncn[8];
      #pragma unroll
      for (int ct = 0; ct < 8; ++ct) ncn[ct] = *(const float4*)&ncnL[nb4 + ct * 16];
      #pragma unroll
      for (int r = 0; r < 4; ++r)
        #pragma unroll
        for (int c = 0; c < 8; ++c) {
          acc[r][c][0] = ncn[c].x; acc[r][c][1] = ncn[c].y;
          acc[r][c][2] = ncn[c].z; acc[r][c][3] = ncn[c].w;
        }
    }

    #pragma unroll 2
    for (int ci = 0; ci < 8; ++ci) {
      const int it = (sub << 3) | ci;
      if (it < 31) asm volatile("s_waitcnt vmcnt(6)" ::: "memory");
      else         asm volatile("s_waitcnt vmcnt(0)" ::: "memory");
      __builtin_amdgcn_s_barrier();
      __builtin_amdgcn_sched_barrier(0);

      if (it + 2 < 32) {
        const int nt2 = it + 2, nsub = nt2 >> 3, nci = nt2 & 7;
        #pragma unroll
        for (int t = 0; t < 2; ++t)
          gld16(srcA[t] + nci * 64, (char*)LDS[nst] + dstA[t]);
        #pragma unroll
        for (int t = 0; t < 4; ++t)
          gld16(srcB[t] + (size_t)nsub * 131072 + nci * 64, (char*)LDS[nst] + dstB[t]);
      }

      const unsigned short* Lb = &LDS[cur][0];
      short8 ah[4];
      #pragma unroll
      for (int rt = 0; rt < 4; ++rt) {
        int row = (wr * 4 + rt) * 16 + qm;
        ah[rt] = *(const short8*)&Lb[row * 32 + sw];
      }
      __builtin_amdgcn_s_setprio(1);
      #pragma unroll
      for (int ch2 = 0; ch2 < 2; ++ch2) {
        short8 bh[4];
        #pragma unroll
        for (int q = 0; q < 4; ++q) {
          int ct = ch2 * 4 + q;
          int r = (wc * 8 + ct) * 16 + qm;
          bh[q] = *(const short8*)&Lb[4096 + r * 32 + sw];
        }
        #pragma unroll
        for (int rt = 0; rt < 4; ++rt)
          #pragma unroll
          for (int q = 0; q < 4; ++q)
            acc[rt][ch2 * 4 + q] =
              __builtin_amdgcn_mfma_f32_16x16x32_bf16(bh[q], ah[rt], acc[rt][ch2 * 4 + q], 0, 0, 0);
      }
      __builtin_amdgcn_s_setprio(0);
      cur = (cur == 2) ? 0 : cur + 1;
      nst = (nst == 2) ? 0 : nst + 1;
    }

    #pragma unroll
    for (int rt = 0; rt < 4; ++rt) {
      float t1 = -3.4e38f, t2 = t1, t3 = t1;
      #pragma unroll
      for (int ct = 0; ct < 8; ++ct)
        #pragma unroll
        for (int rg = 0; rg < 4; ++rg) {
          unsigned idxv = wq | (unsigned)(ct * 16 + rg);
          float kf = __uint_as_float((__float_as_uint(acc[rt][ct][rg]) & kmk) | idxv);
          float n3 = med3(t2, kf, t3);
          float n2 = med3(t1, kf, t2);
          t1 = fmaxf(t1, kf);
          t2 = n2; t3 = n3;
        }
      #pragma unroll
      for (int m = 16; m < 64; m <<= 1) {
        float b1 = __shfl_xor(t1, m), b2 = __shfl_xor(t2, m), b3 = __shfl_xor(t3, m);
        float n3 = med3(t2, b1, t3);
        float n2 = med3(t1, b1, t2);
        t1 = fmaxf(t1, b1); t2 = n2; t3 = n3;
        n3 = med3(t2, b2, t3); t2 = fmaxf(t2, b2); t3 = n3;
        t3 = fmaxf(t3, b3);
      }
      if (quad == 0) {
        int rowl = wr * 64 + rt * 16 + qm;
        mS[wc][rowl][0] = t1; mS[wc][rowl][1] = t2; mS[wc][rowl][2] = t3;
      }
    }
    asm volatile("s_waitcnt lgkmcnt(0)" ::: "memory");
    __builtin_amdgcn_s_barrier();
    __builtin_amdgcn_sched_barrier(0);
    if (tid < 128) {
      float s1 = mS[0][tid][0], s2 = mS[0][tid][1], s3 = mS[0][tid][2];
      float b1 = mS[1][tid][0], b2 = mS[1][tid][1], b3 = mS[1][tid][2];
      float n3 = med3(s2, b1, s3);
      float n2 = med3(s1, b1, s2);
      s1 = fmaxf(s1, b1); s2 = n2; s3 = n3;
      n3 = med3(s2, b2, s3); s2 = fmaxf(s2, b2); s3 = n3;
      s3 = fmaxf(s3, b3);
      unsigned u1 = __float_as_uint(s1), u2 = __float_as_uint(s2), u3 = __float_as_uint(s3);
      uint4 rec;
      rec.x = u1 & kmk;
      rec.y = ((unsigned)f2bf_rne(__uint_as_float(u2 & kmk)) << 16)
            |  (unsigned)f2bf_rne(__uint_as_float(u3 & kmk));
      rec.z = (u1 & 255u) | ((u2 & 255u) << 8) | ((u3 & 255u) << 16);
      rec.w = 0u;
      Rec[(size_t)nbe * N_ + row0 + tid] = rec;
    }
  }
}

// fused post, v9: 16-row tiles (grid 1024 -> 4 blocks/CU, 16 waves/CU) and
// WAVE-parallel refine (each wave owns a flagged row; no block-serial chain).
__global__ __launch_bounds__(256) void k_post(const float* __restrict__ inp,
                                              const float* __restrict__ emb,
                                              const float* __restrict__ cnorm,
                                              const uint4* __restrict__ Rec,
                                              float* __restrict__ out,
                                              float* __restrict__ outIdx,
                                              float* __restrict__ loss) {
  __shared__ float Q[16][258];        // pad 258: out-phase column reads 2-way (free)
  __shared__ float gS[16];
  __shared__ int   ridx[16];
  __shared__ int   flist[16];
  __shared__ int   ckw[4][96];
  __shared__ float cscw[4][96];
  __shared__ int   ncw[4];
  __shared__ int   nflag;
  __shared__ float red[4];

  const int tid = threadIdx.x;
  const int n0 = blockIdx.x * 16, b = n0 >> 10, hw0 = n0 & 1023;
  const int lane = tid & 63, wv = tid >> 6;

  // ---- decide: 16 threads per row (2 subs each), shfl-reduce over 16-lane group ----
  const int r = tid >> 4, j = tid & 15;
  const int row = n0 + r;
  uint4 rv[2];
  rv[0] = Rec[(size_t)(2 * j)     * N_ + row];
  rv[1] = Rec[(size_t)(2 * j + 1) * N_ + row];
  float m1 = -3.4e38f; int gk = 0x7fffffff;
  #pragma unroll
  for (int q = 0; q < 2; ++q) {                  // ascending sub: ties keep lowest gk
    float s1 = __uint_as_float(rv[q].x);
    int  kk = (2 * j + q) * 256 + (int)(rv[q].z & 255u);
    if (s1 > m1) { m1 = s1; gk = kk; }
  }
  #pragma unroll
  for (int m = 1; m < 16; m <<= 1) {
    float so = __shfl_xor(m1, m); int ko = __shfl_xor(gk, m);
    if (so > m1 || (so == m1 && ko < gk)) { m1 = so; gk = ko; }
  }
  float thr = m1 - MARGIN;
  int cnt = 0;
  #pragma unroll
  for (int q = 0; q < 2; ++q) {
    uint4 v = rv[q];
    cnt += (__uint_as_float(v.x) >= thr);
    cnt += (bf2f((unsigned short)(v.y >> 16)) >= thr);
    cnt += (bf2f((unsigned short)(v.y & 0xffffu)) >= thr);
  }
  #pragma unroll
  for (int m = 1; m < 16; m <<= 1) cnt += __shfl_xor(cnt, m);
  if (tid == 0) nflag = 0;
  __syncthreads();
  if (j == 0) {
    gS[r] = m1;
    if (cnt == 1) { ridx[r] = gk; }
    else { int p = atomicAdd(&nflag, 1); flist[p] = r; }
  }
  __syncthreads();

  // ---- wave-parallel exact refine (rare): wave wv handles rows wv, wv+4, ... ----
  int nf = nflag;
  for (int i = wv; i < nf; i += 4) {
    int lr = flist[i];
    int rw = n0 + lr;
    float fr[4];
    #pragma unroll
    for (int k = 0; k < 4; ++k)
      fr[k] = inp[(size_t)b * (C_ * HW_) + (size_t)(lane * 4 + k) * HW_ + (rw & 1023)];
    float th2 = gS[lr] - MARGIN;
    if (lane == 0) ncw[wv] = 0;
    if (lane < 32) {
      uint4 v = Rec[(size_t)lane * N_ + rw];
      float s1 = __uint_as_float(v.x);
      float s2 = bf2f((unsigned short)(v.y >> 16));
      float s3 = bf2f((unsigned short)(v.y & 0xffffu));
      int bb = lane * 256;
      if (s1 >= th2) { int p = atomicAdd(&ncw[wv], 1); ckw[wv][p] = bb + (int)(v.z & 255u); }
      if (s2 >= th2) { int p = atomicAdd(&ncw[wv], 1); ckw[wv][p] = bb + (int)((v.z >> 8) & 255u); }
      if (s3 >= th2) { int p = atomicAdd(&ncw[wv], 1); ckw[wv][p] = bb + (int)((v.z >> 16) & 255u); }
    }
    int nc = ncw[wv];                                  // same-wave DS ordering
    for (int c = 0; c < nc; ++c) {
      int k = ckw[wv][c];
      float4 e = ((const float4*)(emb + (size_t)k * C_))[lane];
      float d = fr[0]*e.x + fr[1]*e.y + fr[2]*e.z + fr[3]*e.w;
      #pragma unroll
      for (int m = 32; m > 0; m >>= 1) d += __shfl_xor(d, m);
      if (lane == 0) cscw[wv][c] = d - cnorm[k];
    }
    if (lane == 0) {
      float bs = cscw[wv][0]; int bk = ckw[wv][0];
      for (int c = 1; c < nc; ++c)
        if (cscw[wv][c] > bs || (cscw[wv][c] == bs && ckw[wv][c] < bk)) { bs = cscw[wv][c]; bk = ckw[wv][c]; }
      ridx[lr] = bk;
    }
  }
  __syncthreads();

  // ---- idx outputs + emb gather (1 float4/thread/pass: wave = one full emb row) ----
  if (tid < 16) outIdx[n0 + tid] = (float)ridx[tid];
  #pragma unroll
  for (int p = 0; p < 4; ++p) {
    int g = p * 256 + tid;
    int rr = g >> 6, c4 = (g & 63) * 4;
    int kq = ridx[rr];
    *(float4*)&Q[rr][c4] = *(const float4*)(emb + (size_t)kq * C_ + c4);
  }
  __syncthreads();

  // ---- NCHW out + loss: float4 on hw (full-line 64B segments) ----
  float lsum = 0.0f;
  const int hw4 = (tid & 3) * 4, cl = tid >> 2;
  #pragma unroll
  for (int p = 0; p < 4; ++p) {
    int c = p * 64 + cl;
    size_t a = (size_t)b * (C_ * HW_) + (size_t)c * HW_ + hw0 + hw4;
    float4 x = *(const float4*)(inp + a);
    float4 q;
    q.x = Q[hw4 + 0][c]; q.y = Q[hw4 + 1][c];
    q.z = Q[hw4 + 2][c]; q.w = Q[hw4 + 3][c];
    *(float4*)(out + a) = q;
    float d0 = q.x - x.x, d1 = q.y - x.y, d2 = q.z - x.z, d3 = q.w - x.w;
    lsum += d0*d0 + d1*d1 + d2*d2 + d3*d3;
  }
  #pragma unroll
  for (int m = 32; m > 0; m >>= 1) lsum += __shfl_xor(lsum, m);
  if ((tid & 63) == 0) red[tid >> 6] = lsum;
  __syncthreads();
  if (tid == 0)
    atomicAdd(loss, (red[0] + red[1] + red[2] + red[3]) * (0.25f / (float)OUT_SZ));
}

// ---------------- fallback path (round-1 fp32, proven) ----------------
__global__ __launch_bounds__(256) void k_norms_fb(const float* __restrict__ emb,
                                                  float* __restrict__ cnorm,
                                                  float* __restrict__ loss_slot) {
  int tid = threadIdx.x, wave = tid >> 6, lane = tid & 63;
  int k = blockIdx.x * 4 + wave;
  float4 v = *(const float4*)(emb + k * C_ + lane * 4);
  float s = v.x*v.x + v.y*v.y + v.z*v.z + v.w*v.w;
  #pragma unroll
  for (int m = 32; m > 0; m >>= 1) s += __shfl_xor(s, m);
  if (lane == 0) cnorm[k] = 0.5f * s;
  if (blockIdx.x == 0 && tid == 0) *loss_slot = 0.0f;
}

__global__ __launch_bounds__(256) void k_score_fb(const float* __restrict__ inp,
                                                  const float* __restrict__ emb,
                                                  const float* __restrict__ cnorm,
                                                  float* __restrict__ bestS,
                                                  int*   __restrict__ bestK) {
  __shared__ float As[16][132];
  __shared__ float Bs[16][132];
  const int tid = threadIdx.x;
  const int tx = tid & 15, ty = tid >> 4;
  const int rt = blockIdx.x >> 3, ks = blockIdx.x & 7;
  const int row0 = rt * 128;
  const float* Abase = inp + (row0 >> 10) * (C_ * HW_) + (row0 & 1023);
  const int kbase = ks * 1024;
  const int m4  = (tid & 31) << 2;
  const int ccA = tid >> 5;
  const int cc4 = (tid & 3) << 2;
  const int kkB = tid >> 2;

  float rS[8]; int rK[8];
  #pragma unroll
  for (int r = 0; r < 8; ++r) { rS[r] = -3.4e38f; rK[r] = 0; }

  for (int kt = 0; kt < 8; ++kt) {
    const int k0 = kbase + kt * 128;
    float acc[8][8];
    #pragma unroll
    for (int r = 0; r < 8; ++r)
      #pragma unroll
      for (int c = 0; c < 8; ++c) acc[r][c] = 0.f;

    for (int ci = 0; ci < 16; ++ci) {
      const int c0 = ci * 16;
      __syncthreads();
      #pragma unroll
      for (int p = 0; p < 2; ++p) {
        int cc = ccA + p * 8;
        float4 v = *(const float4*)(Abase + (c0 + cc) * HW_ + m4);
        *(float4*)(&As[cc][m4]) = v;
      }
      #pragma unroll
      for (int p = 0; p < 2; ++p) {
        int k = kkB + p * 64;
        float4 v = *(const float4*)(emb + (size_t)(k0 + k) * C_ + c0 + cc4);
        Bs[cc4 + 0][k] = v.x; Bs[cc4 + 1][k] = v.y;
        Bs[cc4 + 2][k] = v.z; Bs[cc4 + 3][k] = v.w;
      }
      __syncthreads();
      #pragma unroll
      for (int cc = 0; cc < 16; ++cc) {
        float4 a0 = *(const float4*)(&As[cc][ty * 8]);
        float4 a1 = *(const float4*)(&As[cc][ty * 8 + 4]);
        float4 b0 = *(const float4*)(&Bs[cc][tx * 8]);
        float4 b1 = *(const float4*)(&Bs[cc][tx * 8 + 4]);
        float a[8] = {a0.x, a0.y, a0.z, a0.w, a1.x, a1.y, a1.z, a1.w};
        float b[8] = {b0.x, b0.y, b0.z, b0.w, b1.x, b1.y, b1.z, b1.w};
        #pragma unroll
        for (int r = 0; r < 8; ++r)
          #pragma unroll
          for (int c = 0; c < 8; ++c) acc[r][c] += a[r] * b[c];
      }
    }
    float cn[8];
    {
      float4 c0v = *(const float4*)(cnorm + k0 + tx * 8);
      float4 c1v = *(const float4*)(cnorm + k0 + tx * 8 + 4);
      cn[0] = c0v.x; cn[1] = c0v.y; cn[2] = c0v.z; cn[3] = c0v.w;
      cn[4] = c1v.x; cn[5] = c1v.y; cn[6] = c1v.z; cn[7] = c1v.w;
    }
    #pragma unroll
    for (int r = 0; r < 8; ++r)
      #pragma unroll
      for (int c = 0; c < 8; ++c) {
        float s = acc[r][c] - cn[c];
        if (s > rS[r]) { rS[r] = s; rK[r] = k0 + tx * 8 + c; }
      }
  }
  #pragma unroll
  for (int r = 0; r < 8; ++r) {
    float s = rS[r]; int kk = rK[r];
    #pragma unroll
    for (int m = 1; m < 16; m <<= 1) {
      float so = __shfl_xor(s, m);
      int   ko = __shfl_xor(kk, m);
      if (so > s || (so == s && ko < kk)) { s = so; kk = ko; }
    }
    if (tx == 0) {
      int row = row0 + ty * 8 + r;
      bestS[ks * N_ + row] = s;
      bestK[ks * N_ + row] = kk;
    }
  }
}

__global__ __launch_bounds__(256) void k_merge_fb(const float* __restrict__ bestS,
                                                  const int*   __restrict__ bestK,
                                                  float* __restrict__ out_idx,
                                                  int*   __restrict__ fidx) {
  int n = blockIdx.x * 256 + threadIdx.x;
  float bs = -3.4e38f; int bk = 0x7fffffff;
  #pragma unroll
  for (int s = 0; s < 8; ++s) {
    float v = bestS[s * N_ + n];
    int  kk = bestK[s * N_ + n];
    if (v > bs || (v == bs && kk < bk)) { bs = v; bk = kk; }
  }
  out_idx[n] = (float)bk;
  fidx[n] = bk;
}

__global__ __launch_bounds__(256) void k_out_fb(const float* __restrict__ inp,
                                                const float* __restrict__ emb,
                                                const int* __restrict__ fidx,
                                                float* __restrict__ out,
                                                float* __restrict__ loss) {
  __shared__ float Q[32][260];
  int tid = threadIdx.x;
  int n0 = blockIdx.x * 32, b = n0 >> 10, hw0 = n0 & 1023;
  #pragma unroll
  for (int p = 0; p < 8; ++p) {
    int r = p * 4 + (tid >> 6);
    int kq = fidx[n0 + r];
    float4 v = *(const float4*)(emb + (size_t)kq * C_ + (tid & 63) * 4);
    *(float4*)&Q[r][(tid & 63) * 4] = v;
  }
  __syncthreads();
  int hwl = tid & 31, cl = tid >> 5;
  float lsum = 0.0f;
  #pragma unroll
  for (int p = 0; p < 32; ++p) {
    int c = p * 8 + cl;
    size_t a = (size_t)b * (C_ * HW_) + (size_t)c * HW_ + hw0 + hwl;
    float q = Q[hwl][c];
    float x = inp[a];
    out[a] = q;
    float dd = q - x; lsum += dd * dd;
  }
  #pragma unroll
  for (int m = 32; m > 0; m >>= 1) lsum += __shfl_xor(lsum, m);
  __shared__ float red[4];
  if ((tid & 63) == 0) red[tid >> 6] = lsum;
  __syncthreads();
  if (tid == 0)
    atomicAdd(loss, (red[0] + red[1] + red[2] + red[3]) * (0.25f / (float)OUT_SZ));
}

extern "C" void kernel_launch(void* const* d_in, const int* in_sizes, int n_in,
                              void* d_out, int out_size, void* d_ws, size_t ws_size,
                              hipStream_t stream) {
  const float* inp = (const float*)d_in[0];
  const float* emb = (const float*)d_in[1];
  float* out = (float*)d_out;
  char* ws = (char*)d_ws;

  if (ws_size >= (size_t)WS_NEED) {
    unsigned short* Ah = (unsigned short*)d_out;                      // [0, 8MB) of d_out
    unsigned short* Bh = (unsigned short*)((char*)d_out + 8388608u);  // [8MB, 12MB) of d_out
    uint4* Rec     = (uint4*)(ws + REC_OFF);                          // ws [0, 8MB)
    float* cnorm   = (float*)(ws + CNORM_OFF);
    float* ncnorm  = (float*)(ws + NCNORM_OFF);

    conv_fused <<<3072,  256, 0, stream>>>(inp, emb, Ah, Bh, cnorm, ncnorm,
                                           out + LOSS_OFF);
    k_gemm1p   <<<1024,  256, 0, stream>>>(Ah, Bh, ncnorm, Rec);
    k_post     <<<N_/16, 256, 0, stream>>>(inp, emb, cnorm, Rec, out,
                                           out + IDX_OFF, out + LOSS_OFF);
  } else {
    float* cnorm = (float*)(ws + FB_CNORM);
    float* bestS = (float*)(ws + FB_BESTS);
    int*   bestK = (int*)(ws + FB_BESTK);
    int*   fidx  = (int*)(ws + FB_FIDX);

    k_norms_fb <<<K_ / 4, 256, 0, stream>>>(emb, cnorm, out + LOSS_OFF);
    k_score_fb <<<1024,   256, 0, stream>>>(inp, emb, cnorm, bestS, bestK);
    k_merge_fb <<<N_/256, 256, 0, stream>>>(bestS, bestK, out + IDX_OFF, fidx);
    k_out_fb   <<<OUT_SZ/8192, 256, 0, stream>>>(inp, emb, fidx, out, out + LOSS_OFF);
  }
}